// Round 11
// baseline (219.362 us; speedup 1.0000x reference)
//
#include <hip/hip_runtime.h>
#include <hip/hip_fp16.h>
#include <stdint.h>

#define K_DIM 4096
#define N_OUT 4096
#define BM 256
#define BN 256
#define BKB 256  // K-bytes per step = 8 MFMA K-slices (2 halves of 4)

typedef __attribute__((ext_vector_type(4))) int int32x4;
typedef __attribute__((ext_vector_type(16))) int int32x16;

// ---------------- per-token int4 activation quantization ----------------
// x_scale = max(x_max/7, fp16(1e-5)); x_q = clip(rint(x/x_scale), -8, 7).
// All f32; no intermediate fp16 rounding (matches harness np reference).
__global__ __launch_bounds__(256) void quant_x(const float* __restrict__ x,
                                               int8_t* __restrict__ xq,
                                               float* __restrict__ xs) {
  const int row = blockIdx.x;
  const int t = threadIdx.x;
  const float4* xr = (const float4*)(x + (size_t)row * K_DIM);
  float4 v[4];
  float m = 0.f;
#pragma unroll
  for (int i = 0; i < 4; ++i) {
    v[i] = xr[t * 4 + i];
    m = fmaxf(m, fmaxf(fmaxf(fabsf(v[i].x), fabsf(v[i].y)),
                       fmaxf(fabsf(v[i].z), fabsf(v[i].w))));
  }
#pragma unroll
  for (int off = 32; off > 0; off >>= 1) m = fmaxf(m, __shfl_xor(m, off));
  __shared__ float wmax[4];
  if ((t & 63) == 0) wmax[t >> 6] = m;
  __syncthreads();
  m = fmaxf(fmaxf(wmax[0], wmax[1]), fmaxf(wmax[2], wmax[3]));

  const float eps = 1.0013580322265625e-05f;  // fp16(1e-5) as f32
  const float xscale = fmaxf(m / 7.0f, eps);
  if (t == 0) xs[row] = xscale;

  uint32_t p[4];
#pragma unroll
  for (int g = 0; g < 4; ++g) {
    const float* fv = (const float*)&v[g];
    uint32_t w = 0;
#pragma unroll
    for (int j = 0; j < 4; ++j) {
      float r = rintf(fv[j] / xscale);
      r = fminf(fmaxf(r, -8.f), 7.f);
      w |= ((uint32_t)(uint8_t)(int8_t)(int)r) << (8 * j);
    }
    p[g] = w;
  }
  *(uint4*)(xq + (size_t)row * K_DIM + t * 16) = *(uint4*)p;
}

// ---------------- weight pack: int32 -> int8, FRAGMENT-MAJOR ----------------
// block b = nfrag*128 + kslice; each block 1024B in MFMA lane order.
__global__ __launch_bounds__(256) void pack_w(const int* __restrict__ w,
                                              uint32_t* __restrict__ wqf) {
  const int c = blockIdx.x * 256 + threadIdx.x;  // one thread per 16B chunk
  const int blk = c >> 6;
  const int l = c & 63;
  const int row = ((blk >> 7) << 5) + (l & 31);
  const int k = ((blk & 127) << 5) + ((l >> 5) << 4);
  const int4* src = (const int4*)(w + (size_t)row * K_DIM + k);  // 16 ints
  uint32_t p[4];
#pragma unroll
  for (int g = 0; g < 4; ++g) {
    const int4 v = src[g];
    p[g] = (uint32_t)(v.x & 255) | ((uint32_t)(v.y & 255) << 8) |
           ((uint32_t)(v.z & 255) << 16) | ((uint32_t)(v.w & 255) << 24);
  }
  *(uint4*)(wqf + (size_t)c * 4) = *(uint4*)p;
}

// ---------------- i8 GEMM: out = dequant(xq . wq^T) ----------------
// 256x256 tile, 8 waves (2m x 4n, 512 thr), wave tile 128x64, 32x32x32 i8.
// r11 = r8 skeleton with BKB 128 -> 256 (overhead amortization):
//  - 16 steps, ONE barrier per step, ZERO vmcnt in the main loop.
//  - A: LDS fragment-contiguous (64 blocks of 1KB: fa*8+ks), 2-deep
//    (2x64KB = 128KB), global_load_lds (8 per wave per step).
//  - B: frag-major global -> regs; bA = current H0 (ks 0-3), bB = current H1
//    (ks 4-7); bA reloaded mid-step for next step's H0 (after last bA use).
//  - In-order vmcnt retire makes explicit waits unnecessary: H1's MFMA
//    reg-deps on bB (issued AFTER this step's A-staging) transitively drain
//    A(s+1) before the barrier; B(s+1,H0) stays in flight across the barrier
//    and is drained by next step's first MFMA reg-dep.
// Register ledger (unchanged from r8): acc 128 + a0/a1 32 + bA/bB 64 +
// addressing ~30 ~= 236/wave -> 2 waves/SIMD (the unified-file wall).
__global__ __launch_bounds__(512, 2) void gemm_w4a4(
    const int8_t* __restrict__ xq, const uint8_t* __restrict__ wqf,
    const float* __restrict__ xs, const float* __restrict__ wscale,
    float* __restrict__ out, int M) {
  __shared__ uint8_t lds[2][65536];  // A only: 64 frag-blocks (8 fa x 8 ks)/buf

  // Swizzle: A-panels XCD-exclusive (L2-resident); concurrent blocks in an
  // XCD share A via L2.
  const int bid = blockIdx.x;
  const int xcd = bid & 7;
  const int i_loc = bid >> 3;            // 0..63
  const int mt = xcd * 4 + (i_loc & 3);  // 0..31, XCD-exclusive
  const int nt = i_loc >> 2;             // 0..15
  const int tm = mt * BM;
  const int tn = nt * BN;

  const int t = threadIdx.x;  // 0..511
  const int l = t & 63;
  const int wv = t >> 6;      // 0..7
  const int wm = wv >> 2;     // 0..1
  const int wn = wv & 3;      // 0..3

  // A staging source: lane l covers row (l&31), k-bytes (l>>5)*16
  const uint8_t* gA = (const uint8_t*)xq + (size_t)tm * K_DIM +
                      (size_t)(l & 31) * K_DIM + ((l >> 5) << 4);
  // B fragment-major bases for this wave's two n-frags
  const int nfrag0 = nt * 8 + wn * 2;
  const uint8_t* gB0 = wqf + ((size_t)(nfrag0 * 128) << 10) + l * 16;
  const uint8_t* gB1 = wqf + ((size_t)((nfrag0 + 1) * 128) << 10) + l * 16;

  int32x16 acc[4][2] = {};

  // stage step tile (ktb) into buf: wave wv stages ks=wv for all 8 fa;
  // block (fa,ks) at LDS offset (fa*8+ks)*1024; dest = q*8192 + t*16
  // (wave-uniform base + lane*16, as global_load_lds requires).
  auto stageA = [&](int buf, int ktb) {
#pragma unroll
    for (int q = 0; q < 8; ++q) {
      __builtin_amdgcn_global_load_lds(
          (const __attribute__((address_space(1))) uint32_t*)(
              gA + (size_t)(q * 32) * K_DIM + wv * 32 + ktb),
          (__attribute__((address_space(3))) uint32_t*)(
              &lds[buf][q * 8192 + t * 16]),
          16, 0, 0);
    }
  };

  // load 8 B frags (2 nfrag x 4 ks) starting at global kslice ksg
  auto loadB = [&](int32x4 (&b)[8], int ksg) {
#pragma unroll
    for (int j = 0; j < 4; ++j) {
      b[j] = *(const int32x4*)(gB0 + ((size_t)(ksg + j) << 10));
      b[4 + j] = *(const int32x4*)(gB1 + ((size_t)(ksg + j) << 10));
    }
  };

#define LDA4(dst, ks)                                                \
  _Pragma("unroll") for (int m_ = 0; m_ < 4; ++m_) dst[m_] =         \
      *(const int32x4*)(base + m_ * 8192 + (ks) * 1024);

#define M8(A, B, k)                                                          \
  _Pragma("unroll") for (int m_ = 0; m_ < 4; ++m_) {                         \
    acc[m_][0] = __builtin_amdgcn_mfma_i32_32x32x32_i8(A[m_], B[k],          \
                                                       acc[m_][0], 0, 0, 0); \
    acc[m_][1] = __builtin_amdgcn_mfma_i32_32x32x32_i8(A[m_], B[4 + (k)],    \
                                                       acc[m_][1], 0, 0, 0); \
  }

  const int nsteps = K_DIM / BKB;  // 16

  // prologue: A(0)->buf0, B(0,H0)->bA; vmcnt(8) retires exactly A(0)
  int32x4 bA[8], bB[8];
  stageA(0, 0);
  asm volatile("" ::: "memory");  // pin: A-stages before B-loads (ledger)
  loadB(bA, 0);
  asm volatile("s_waitcnt vmcnt(8)" ::: "memory");
  __builtin_amdgcn_s_barrier();

  for (int s = 0; s < nsteps; ++s) {
    const int buf = s & 1;
    stageA(buf ^ 1, ((s + 1) & 15) * BKB);  // A(s+1) (wrapped dead at tail)
    asm volatile("" ::: "memory");          // pin VMEM order
    loadB(bB, s * 8 + 4);                   // B(s, H1)
    asm volatile("" ::: "memory");

    const uint8_t* base = &lds[buf][wm * 32768 + l * 16];
    int32x4 a0[4], a1[4];
    LDA4(a0, 0);
    LDA4(a1, 1);
    M8(a0, bA, 0);
    LDA4(a0, 2);
    M8(a1, bA, 1);
    LDA4(a1, 3);
    M8(a0, bA, 2);
    LDA4(a0, 4);
    M8(a1, bA, 3);
    // last bA use done -> refill bA with B(s+1, H0); issued after bB (ledger)
    loadB(bA, ((s + 1) & 15) * 8);
    asm volatile("" ::: "memory");
    LDA4(a1, 5);
    M8(a0, bB, 0);
    LDA4(a0, 6);
    M8(a1, bB, 1);
    LDA4(a1, 7);
    M8(a0, bB, 2);
    M8(a1, bB, 3);
    // bB reg-deps drained [A(s+1), B(s,H1)]; only B(s+1,H0) crosses barrier
    __builtin_amdgcn_s_barrier();
  }
  asm volatile("s_waitcnt vmcnt(0)" ::: "memory");  // drain dead prefetches

#undef LDA4
#undef M8

  // epilogue: dequant + fp16-round, write f32
  const int colbase = tn + wn * 64;
  const int rowbase = tm + wm * 128 + 4 * (l >> 5);
#pragma unroll
  for (int m = 0; m < 4; ++m) {
#pragma unroll
    for (int n = 0; n < 2; ++n) {
      const int col = colbase + n * 32 + (l & 31);
      const float wsc = wscale[col];
#pragma unroll
      for (int j = 0; j < 16; ++j) {
        const int row = rowbase + m * 32 + (j & 3) + 8 * (j >> 2);
        const float val = (float)acc[m][n][j] * (xs[row] * wsc);
        out[(size_t)row * N_OUT + col] = __half2float(__float2half(val));
      }
    }
  }
}

extern "C" void kernel_launch(void* const* d_in, const int* in_sizes, int n_in,
                              void* d_out, int out_size, void* d_ws, size_t ws_size,
                              hipStream_t stream) {
  const float* x = (const float*)d_in[0];    // fp16 values as f32
  const int* w = (const int*)d_in[1];        // int4-range values as i32
  const float* wsc = (const float*)d_in[2];  // fp16 values as f32
  float* out = (float*)d_out;

  const int M = in_sizes[0] / K_DIM;  // 8192 tokens

  uint8_t* ws = (uint8_t*)d_ws;
  int8_t* xq = (int8_t*)ws;                              // M*K bytes
  uint8_t* wqf = ws + (size_t)M * K_DIM;                 // N*K bytes (frag-major)
  float* xs = (float*)(ws + (size_t)M * K_DIM + (size_t)N_OUT * K_DIM);

  quant_x<<<M, 256, 0, stream>>>(x, xq, xs);
  pack_w<<<(N_OUT * K_DIM / 16) / 256, 256, 0, stream>>>(w, (uint32_t*)wqf);
  gemm_w4a4<<<(M / BM) * (N_OUT / BN), 512, 0, stream>>>(
      xq, wqf, xs, wsc, out, M);
}